// Round 6
// baseline (1566.946 us; speedup 1.0000x reference)
//
#include <hip/hip_runtime.h>

// MultilayerGRU — reference's indexing bug makes every (b,t) independent:
// 7 chained GEMMs over a 65536x512 activation matrix.
// Round 6: "B-in-registers" persistent GEMM. Evidence from rounds 1-5: every
// global_load_lds-staged structure walls at ~12-17 B/cyc/CU LDS ingest and/or
// per-phase barrier drains (conflict-free + low-fetch variants were NOT faster).
// New structure: each wave holds its 32-col B-slice in 128 VGPRs (loaded once);
// A staged per 64-row M-tile as a whole-K [64][512] LDS tile via plain
// global->reg->ds_write (normal load path ~60 B/cyc/CU), XOR-swizzled; only 2
// __syncthreads per M-tile, next-tile A prefetch issued under ~2500 cyc of MFMA.

typedef __attribute__((ext_vector_type(4))) float f32x4;
typedef __attribute__((ext_vector_type(8))) __bf16 bf16x8;

#define NROWS 65536          // B*S
#define HID_OFF 33554432ull  // B*S*O floats, start of hidden_out in d_out

__device__ __forceinline__ float sigmoidf_(float x) { return 1.f / (1.f + __expf(-x)); }
__device__ __forceinline__ float tanh_fast(float x) {
  const float e = __expf(2.f * x);
  return 1.f - 2.f / (e + 1.f);
}

// EPI: 0 = gates (N=1536: z|r|gpart), 1 = update (N=512), 2 = out GEMM (N=512)
// Block: 512 threads = 8 waves; block owns a 256-col strip; wave owns 32 cols.
// Per M-tile (64 rows): stage A[64][512] to LDS (reg-staged, swizzled), then
// 16 k-steps of {4 ds_read + 8 MFMA} per wave against register-resident B.
template<int EPI, bool L0>
__global__ __launch_bounds__(512, 2) void gemm_breg(
    const __bf16* __restrict__ A,    // chunk_rows x 512
    const __bf16* __restrict__ Bt,   // N x 512 (pre-transposed weights, pre-offset)
    int NS, int P, int mtiles, int row_off,
    const float* __restrict__ bias,
    const float* __restrict__ cterm,  // L0: 64 x 1024 fp32
    const float* __restrict__ h0f,    // L0: hidden_state base (B x 3*512)
    const __bf16* __restrict__ haux,  // L>=1: h_in buffer
    const __bf16* __restrict__ gp_in,
    const __bf16* __restrict__ z_in,
    __bf16* __restrict__ o_z, __bf16* __restrict__ o_rh, __bf16* __restrict__ o_gp,
    __bf16* __restrict__ o_h, float* __restrict__ o_f)
{
  __shared__ alignas(16) __bf16 As[64 * 512];   // 64 KB, whole-K A tile

  const int tid = threadIdx.x, lane = tid & 63, w = tid >> 6;
  const int strip = blockIdx.x % NS;
  const int j0    = blockIdx.x / NS;
  const int c0    = strip * 256 + w * 32;   // wave's first output column

  // ---- B-slice into registers: breg[ni][t], ni: 2x16 cols, t: 16 k-steps of 32
  bf16x8 breg[2][16];
  {
    const __bf16* bp = Bt + (size_t)(c0 + (lane & 15)) * 512 + (lane >> 4) * 8;
#pragma unroll
    for (int ni = 0; ni < 2; ++ni)
#pragma unroll
      for (int t = 0; t < 16; ++t)
        breg[ni][t] = *(const bf16x8*)(bp + (size_t)ni * 16 * 512 + t * 32);
  }

  const int fcol = lane & 15;
  const int frow = (lane >> 4) * 4;

  // staged A chunks: lane handles rows w+8i, contiguous 16B at col lane*8 (1KB/row)
  bf16x8 r[8];
  if (j0 < mtiles) {
    const __bf16* Ab = A + (size_t)j0 * 64 * 512;
#pragma unroll
    for (int i = 0; i < 8; ++i)
      r[i] = *(const bf16x8*)(Ab + (size_t)(w + 8 * i) * 512 + lane * 8);
  }

  for (int mt = j0; mt < mtiles; mt += P) {
    // ---- stage A: LDS[row][slot] = global[row][slot ^ (row&7)]; here row&7 == w,
    // lane holds global chunk q=lane -> slot = lane ^ w.
#pragma unroll
    for (int i = 0; i < 8; ++i) {
      const int row = w + 8 * i;
      *(bf16x8*)(As + row * 512 + (lane ^ w) * 8) = r[i];
    }
    __syncthreads();   // tile staged (lgkm drained by barrier)

    // ---- prefetch next M-tile's A (flies under the compute below)
    if (mt + P < mtiles) {
      const __bf16* Ab = A + (size_t)(mt + P) * 64 * 512;
#pragma unroll
      for (int i = 0; i < 8; ++i)
        r[i] = *(const bf16x8*)(Ab + (size_t)(w + 8 * i) * 512 + lane * 8);
    }

    // ---- compute: 16 k-steps, A frags from LDS (swizzled), B from registers
    f32x4 acc[4][2];
#pragma unroll
    for (int i = 0; i < 4; ++i) {
      acc[i][0] = (f32x4){0.f, 0.f, 0.f, 0.f};
      acc[i][1] = (f32x4){0.f, 0.f, 0.f, 0.f};
    }
#pragma unroll
    for (int t = 0; t < 16; ++t) {
      bf16x8 af[4];
#pragma unroll
      for (int mi = 0; mi < 4; ++mi) {
        const int row  = mi * 16 + (lane & 15);
        const int slot = (t * 4 + (lane >> 4)) ^ (row & 7);
        af[mi] = *(const bf16x8*)(As + row * 512 + slot * 8);
      }
#pragma unroll
      for (int mi = 0; mi < 4; ++mi) {
        acc[mi][0] = __builtin_amdgcn_mfma_f32_16x16x32_bf16(af[mi], breg[0][t], acc[mi][0], 0, 0, 0);
        acc[mi][1] = __builtin_amdgcn_mfma_f32_16x16x32_bf16(af[mi], breg[1][t], acc[mi][1], 0, 0, 0);
      }
    }

    // ---- epilogue — C/D layout (m89): col = lane&15, row = (lane>>4)*4 + reg
#pragma unroll
    for (int mi = 0; mi < 4; ++mi) {
#pragma unroll
      for (int ni = 0; ni < 2; ++ni) {
#pragma unroll
        for (int j = 0; j < 4; ++j) {
          const int rloc = mt * 64 + mi * 16 + frow + j;
          const int gcol = c0 + ni * 16 + fcol;
          const int grow = row_off + rloc;
          const int b = grow >> 10;
          float c = acc[mi][ni][j];
          if (EPI == 0) {
            c += bias[gcol];
            if (gcol < 512) {                       // z gate
              if (L0) c += cterm[b * 1024 + gcol];
              o_z[(size_t)rloc * 512 + gcol] = (__bf16)sigmoidf_(c);
            } else if (gcol < 1024) {               // r gate -> r*h
              const int nn = gcol - 512;
              if (L0) c += cterm[b * 1024 + gcol];
              const float rv = sigmoidf_(c);
              const float h = L0 ? h0f[b * 1536 + nn] : (float)haux[(size_t)rloc * 512 + nn];
              o_rh[(size_t)rloc * 512 + nn] = (__bf16)(rv * h);
            } else {                                // g partial (x@Wgx + bgx)
              o_gp[(size_t)rloc * 512 + (gcol - 1024)] = (__bf16)c;
            }
          } else if (EPI == 1) {
            const float gv = tanh_fast((float)gp_in[(size_t)rloc * 512 + gcol] + c);
            const float zv = (float)z_in[(size_t)rloc * 512 + gcol];
            const float h = L0 ? h0f[b * 1536 + gcol] : (float)haux[(size_t)rloc * 512 + gcol];
            const float hv = zv * h + (1.f - zv) * gv;
            o_h[(size_t)rloc * 512 + gcol] = (__bf16)hv;
            if (o_f && ((grow & 1023) == 1023))     // fused extract_h
              o_f[(size_t)b * 1536 + gcol] = (float)(__bf16)hv;
          } else {
            o_f[(size_t)rloc * 512 + gcol] = c + bias[gcol];
          }
        }
      }
    }
    __syncthreads();   // all waves' ds_reads done before next tile's ds_write
  }
}

// ---- prep kernels (unchanged, passing) ----

__global__ void prep_pack(const float* __restrict__ Wzx, const float* __restrict__ Wzh,
                          const float* __restrict__ Wrx, const float* __restrict__ Wrh,
                          const float* __restrict__ Wgx, const float* __restrict__ Wgh,
                          const float* __restrict__ Wout,
                          __bf16* __restrict__ W1t, __bf16* __restrict__ Wght,
                          __bf16* __restrict__ Woutt)
{
  const int slot = blockIdx.z;
  const float* srcA;
  const float* srcB = nullptr;
  __bf16* dst;
  if (slot < 9) {
    const int l = slot / 3, g = slot % 3;
    srcA = (g == 0 ? Wzx : g == 1 ? Wrx : Wgx) + (size_t)l * 512 * 512;
    if (l > 0 && g < 2) srcB = (g == 0 ? Wzh : Wrh) + (size_t)l * 512 * 512;
    dst = W1t + (size_t)l * 1536 * 512 + (size_t)g * 512 * 512;
  } else if (slot < 12) {
    const int l = slot - 9;
    srcA = Wgh + (size_t)l * 512 * 512;
    dst = Wght + (size_t)l * 512 * 512;
  } else {
    srcA = Wout;
    dst = Woutt;
  }
  __shared__ float tile[32][33];
  const int k0 = blockIdx.x * 32;
  const int n0 = blockIdx.y * 32;
  const int tx = threadIdx.x;
  const int ty = threadIdx.y;
  for (int i = ty; i < 32; i += 8) {
    float v = srcA[(size_t)(k0 + i) * 512 + n0 + tx];
    if (srcB) v += srcB[(size_t)(k0 + i) * 512 + n0 + tx];
    tile[i][tx] = v;
  }
  __syncthreads();
  for (int i = ty; i < 32; i += 8)
    dst[(size_t)(n0 + i) * 512 + k0 + tx] = (__bf16)tile[tx][i];
}

__global__ void cterm_kernel(const float* __restrict__ hidden,
                             const float* __restrict__ Wzh,
                             const float* __restrict__ Wrh,
                             float* __restrict__ Cterm)
{
  const int idx = blockIdx.x * blockDim.x + threadIdx.x;
  const int b = idx >> 10;
  const int n = idx & 1023;
  const float* W = (n < 512 ? Wzh : Wrh);
  const int nn = n & 511;
  const float* h0 = hidden + (size_t)b * 1536;
  float acc = 0.f;
  for (int k = 0; k < 512; ++k) acc += h0[k] * W[(size_t)k * 512 + nn];
  Cterm[idx] = acc;
}

__global__ void small_prep(const float* __restrict__ bzx, const float* __restrict__ brx,
                           const float* __restrict__ bgx, const float* __restrict__ hidden,
                           float* __restrict__ bias1, float* __restrict__ out_hidden)
{
  const int idx = blockIdx.x * blockDim.x + threadIdx.x;
  if (idx < 3 * 1536) {
    const int l = idx / 1536, j = idx % 1536;
    const float* src = (j < 512 ? bzx : j < 1024 ? brx : bgx);
    bias1[idx] = src[l * 512 + (j & 511)];
  }
  const int hidx = idx - 3 * 1536;
  if (hidx >= 0 && hidx < 64 * 512) {
    const int b = hidx >> 9, n = hidx & 511;
    out_hidden[(size_t)b * 1536 + n] = hidden[(size_t)b * 1536 + n];
  }
}

__global__ void convert_x(const float* __restrict__ src, __bf16* __restrict__ dst, long n)
{
  const long i = ((long)blockIdx.x * blockDim.x + threadIdx.x) * 8;
  if (i >= n) return;
  const f32x4 a = *(const f32x4*)(src + i);
  const f32x4 b = *(const f32x4*)(src + i + 4);
  bf16x8 o;
  o[0] = (__bf16)a[0]; o[1] = (__bf16)a[1]; o[2] = (__bf16)a[2]; o[3] = (__bf16)a[3];
  o[4] = (__bf16)b[0]; o[5] = (__bf16)b[1]; o[6] = (__bf16)b[2]; o[7] = (__bf16)b[3];
  *(bf16x8*)(dst + i) = o;
}

extern "C" void kernel_launch(void* const* d_in, const int* in_sizes, int n_in,
                              void* d_out, int out_size, void* d_ws, size_t ws_size,
                              hipStream_t stream) {
  const float* input  = (const float*)d_in[0];
  const float* hidden = (const float*)d_in[1];
  const float* Wzx = (const float*)d_in[2];
  const float* bzx = (const float*)d_in[3];
  const float* Wzh = (const float*)d_in[4];
  const float* Wrx = (const float*)d_in[5];
  const float* brx = (const float*)d_in[6];
  const float* Wrh = (const float*)d_in[7];
  const float* Wgx = (const float*)d_in[8];
  const float* bgx = (const float*)d_in[9];
  const float* Wgh = (const float*)d_in[10];
  const float* Wout = (const float*)d_in[11];
  const float* bout = (const float*)d_in[12];

  float* out = (float*)d_out;
  float* out_hidden = out + HID_OFF;

  char* ws = (char*)d_ws;
  size_t off = 0;
  auto carve = [&](size_t bytes) -> void* {
    off = (off + 255) & ~(size_t)255;
    void* p = ws + off;
    off += bytes;
    return p;
  };

  __bf16* W1t   = (__bf16*)carve(3ull * 1536 * 512 * 2);
  __bf16* Wght  = (__bf16*)carve(3ull * 512 * 512 * 2);
  __bf16* Woutt = (__bf16*)carve(512ull * 512 * 2);
  float*  bias1 = (float*) carve(3ull * 1536 * 4);
  float*  Cterm = (float*) carve(64ull * 1024 * 4);
  const size_t fixed_end = off;

  long chunk_rows = NROWS;
  int C = 1;
  while (C < 32) {
    const size_t need = ((fixed_end + 255) & ~(size_t)255) +
                        5ull * (size_t)chunk_rows * 512 * 2 + 5 * 256;
    if (need <= ws_size) break;
    C *= 2;
    chunk_rows /= 2;
  }
  __bf16* bufA = (__bf16*)carve((size_t)chunk_rows * 512 * 2);
  __bf16* bufB = (__bf16*)carve((size_t)chunk_rows * 512 * 2);
  __bf16* zb   = (__bf16*)carve((size_t)chunk_rows * 512 * 2);
  __bf16* rhb  = (__bf16*)carve((size_t)chunk_rows * 512 * 2);
  __bf16* gpb  = (__bf16*)carve((size_t)chunk_rows * 512 * 2);

  small_prep<<<(3 * 1536 + 64 * 512 + 255) / 256, 256, 0, stream>>>(
      bzx, brx, bgx, hidden, bias1, out_hidden);
  dim3 tp_grid(16, 16, 13), tp_blk(32, 8);
  prep_pack<<<tp_grid, tp_blk, 0, stream>>>(Wzx, Wzh, Wrx, Wrh, Wgx, Wgh, Wout,
                                            W1t, Wght, Woutt);
  cterm_kernel<<<65536 / 256, 256, 0, stream>>>(hidden, Wzh, Wrh, Cterm);

  for (int c = 0; c < C; ++c) {
    const long row_off = (long)c * chunk_rows;
    const long nelem = chunk_rows * 512;
    const int mtiles = (int)(chunk_rows / 64);

    convert_x<<<(int)((nelem / 8 + 255) / 256), 256, 0, stream>>>(
        input + (size_t)row_off * 512, bufA, nelem);

    // gates: NS=6 strips (256 cols each), P=42 -> 252 blocks (1/CU, co-resident)
    // update/out: NS=2, P=128 -> 256 blocks
    // layer 0
    gemm_breg<0, true><<<6 * 42, 512, 0, stream>>>(
        bufA, W1t, 6, 42, mtiles, (int)row_off, bias1, Cterm, hidden, nullptr,
        nullptr, nullptr, zb, rhb, gpb, nullptr, nullptr);
    gemm_breg<1, true><<<2 * 128, 512, 0, stream>>>(
        rhb, Wght, 2, 128, mtiles, (int)row_off, nullptr, nullptr, hidden, nullptr,
        gpb, zb, nullptr, nullptr, nullptr, bufB, out_hidden + 512);

    // layer 1 (x == h == bufB)
    gemm_breg<0, false><<<6 * 42, 512, 0, stream>>>(
        bufB, W1t + 1536 * 512, 6, 42, mtiles, (int)row_off, bias1 + 1536, nullptr,
        nullptr, bufB, nullptr, nullptr, zb, rhb, gpb, nullptr, nullptr);
    gemm_breg<1, false><<<2 * 128, 512, 0, stream>>>(
        rhb, Wght + 512 * 512, 2, 128, mtiles, (int)row_off, nullptr, nullptr,
        nullptr, bufB, gpb, zb, nullptr, nullptr, nullptr, bufA, out_hidden + 1024);

    // layer 2 (x == h == bufA)
    gemm_breg<0, false><<<6 * 42, 512, 0, stream>>>(
        bufA, W1t + 2 * 1536 * 512, 6, 42, mtiles, (int)row_off, bias1 + 3072, nullptr,
        nullptr, bufA, nullptr, nullptr, zb, rhb, gpb, nullptr, nullptr);
    gemm_breg<1, false><<<2 * 128, 512, 0, stream>>>(
        rhb, Wght + 2 * 512 * 512, 2, 128, mtiles, (int)row_off, nullptr, nullptr,
        nullptr, bufA, gpb, zb, nullptr, nullptr, nullptr, bufB, nullptr);

    // output projection
    gemm_breg<2, false><<<2 * 128, 512, 0, stream>>>(
        bufB, Woutt, 2, 128, mtiles, (int)row_off, bout, nullptr, nullptr, nullptr,
        nullptr, nullptr, nullptr, nullptr, nullptr, nullptr,
        out + (size_t)row_off * 512);
  }
}

// Round 7
// 927.523 us; speedup vs baseline: 1.6894x; 1.6894x over previous
//
#include <hip/hip_runtime.h>

// MultilayerGRU — reference's indexing bug makes every (b,t) independent:
// 7 chained GEMMs over a 65536x512 activation matrix.
// Round 7: model-driven fixes on the R4 skeleton (128x128 tile, 4-wave, TLP):
//  (1) BK=32 double-buffered async k-loop: raw s_barrier + vmcnt(0)-after-MFMA,
//      16 k-steps, 32KB LDS -> 4 blocks/CU kept.
//  (2) z / g-partial relayed in FRAGMENT order (gates stores per-lane-contiguous;
//      update reads coalesced b128) — kills ~4096 scalar 2B loads per update wave.
//  (3) haux (h input) LDS-tiled in epilogues instead of scattered 2B reads.

typedef __attribute__((ext_vector_type(4))) float f32x4;
typedef __attribute__((ext_vector_type(8))) __bf16 bf16x8;

#define NROWS 65536          // B*S
#define HID_OFF 33554432ull  // B*S*O floats, start of hidden_out in d_out

__device__ __forceinline__ void gload16(const void* g, void* l) {
  __builtin_amdgcn_global_load_lds((const __attribute__((address_space(1))) void*)g,
                                   (__attribute__((address_space(3))) void*)l,
                                   16, 0, 0);
}
__device__ __forceinline__ float sigmoidf_(float x) { return 1.f / (1.f + __expf(-x)); }
__device__ __forceinline__ float tanh_fast(float x) {
  const float e = __expf(2.f * x);
  return 1.f - 2.f / (e + 1.f);
}

// Stage one 128x32 bf16 tile (8KB) with 256 threads into linear LDS;
// global source pre-permuted with involution cc = (s&3)^(row&3) on 16B chunks.
__device__ __forceinline__ void stage32(const __bf16* __restrict__ src, int k0,
                                        __bf16* lds, int w, int lane) {
#pragma unroll
  for (int i = 0; i < 2; ++i) {
    const int s0 = (w * 2 + i) * 64;   // wave-uniform chunk base
    const int s = s0 + lane;           // chunk 0..511
    const int row = s >> 2;            // 0..127
    const int cc = (s ^ row) & 3;      // source chunk within row
    gload16(src + (size_t)row * 512 + k0 + cc * 8, lds + s0 * 8);
  }
}

// Swizzled fragment read from a [128][32] tile: chunk = (lane>>4) ^ (row&3).
__device__ __forceinline__ bf16x8 frag32(const __bf16* t, int row, int lane) {
  const int c = ((lane >> 4) ^ row) & 3;
  return *(const bf16x8*)(t + row * 32 + c * 8);
}

// Stage a 128x128 bf16 tile of haux (512-col row-major) into 32KB LDS.
__device__ __forceinline__ void stage_ht(const __bf16* __restrict__ src,
                                         __bf16* Ht, int w, int lane) {
#pragma unroll
  for (int i = 0; i < 8; ++i) {
    const int s0 = i * 256 + w * 64;   // 16B chunks, 16 per row
    const int s = s0 + lane;
    const int row = s >> 4, cc = s & 15;
    gload16(src + (size_t)row * 512 + cc * 8, Ht + s0 * 8);
  }
  asm volatile("s_waitcnt vmcnt(0)");
  __builtin_amdgcn_sched_barrier(0);
  __builtin_amdgcn_s_barrier();
  __builtin_amdgcn_sched_barrier(0);
}

// EPI: 0 = gates (N=1536: z|r|gpart), 1 = update (N=512), 2 = out (N=512)
template<int EPI, bool L0>
__global__ __launch_bounds__(256, 4) void gemm7(
    const __bf16* __restrict__ A,     // M x 512 row-major
    const __bf16* __restrict__ Bt,    // N x 512 (pre-transposed weights)
    int tiles_n, int row_off,
    const float* __restrict__ bias,
    const float* __restrict__ cterm,  // L0 gates: 64 x 1024 fp32
    const float* __restrict__ h0f,    // L0: hidden_state base (B x 3*512)
    const __bf16* __restrict__ haux,  // L>=1: h row-major
    const __bf16* __restrict__ zf,    // fragment buffer (EPI0 write / EPI1 read)
    const __bf16* __restrict__ gf,    // fragment buffer (EPI0 write / EPI1 read)
    __bf16* __restrict__ o_rh,        // EPI0: r*h row-major
    __bf16* __restrict__ o_h,         // EPI1: h row-major
    float* __restrict__ o_f)          // EPI1: hidden_out slot; EPI2: out
{
  __shared__ alignas(16) __bf16 smem[16384];   // 32KB: k-loop dbuf, reused as Ht
  __bf16* const A0 = smem;
  __bf16* const B0 = smem + 4096;
  __bf16* const A1 = smem + 8192;
  __bf16* const B1 = smem + 12288;

  const int tid = threadIdx.x, lane = tid & 63, w = tid >> 6;

  // T1: bijective XCD swizzle (m204)
  int bid = blockIdx.x;
  {
    const int nwg = gridDim.x;
    const int q = nwg >> 3, r = nwg & 7;
    const int x = bid & 7, rest = bid >> 3;
    bid = (x < r ? x * (q + 1) : r * (q + 1) + (x - r) * q) + rest;
  }
  const int tm = bid / tiles_n;
  const int tn = bid - tm * tiles_n;
  const size_t arow0 = (size_t)tm * 128;
  const int brow0 = tn * 128;
  const __bf16* const Ab = A + arow0 * 512;
  const __bf16* const Bb = Bt + (size_t)brow0 * 512;

  const int wr = (w >> 1) * 64;
  const int wc = (w & 1) * 64;

  f32x4 acc[4][4];
  const f32x4 zz = {0.f, 0.f, 0.f, 0.f};
#pragma unroll
  for (int i = 0; i < 4; ++i)
#pragma unroll
    for (int j = 0; j < 4; ++j) acc[i][j] = zz;

  // one async k-step: stage t+1 into nxt, compute t from cur, counted wait
  auto step = [&](int t, const __bf16* cA, const __bf16* cB,
                  __bf16* nA, __bf16* nB) {
    if (t < 15) {
      stage32(Ab, (t + 1) * 32, nA, w, lane);
      stage32(Bb, (t + 1) * 32, nB, w, lane);
    }
    bf16x8 af[4], bb4[4];
#pragma unroll
    for (int i = 0; i < 4; ++i) {
      af[i]  = frag32(cA, wr + i * 16 + (lane & 15), lane);
      bb4[i] = frag32(cB, wc + i * 16 + (lane & 15), lane);
    }
#pragma unroll
    for (int mi = 0; mi < 4; ++mi)
#pragma unroll
      for (int ni = 0; ni < 4; ++ni)
        acc[mi][ni] = __builtin_amdgcn_mfma_f32_16x16x32_bf16(af[mi], bb4[ni], acc[mi][ni], 0, 0, 0);
    if (t < 15) {
      asm volatile("s_waitcnt vmcnt(0)");
      __builtin_amdgcn_sched_barrier(0);
    }
    __builtin_amdgcn_sched_barrier(0);
    __builtin_amdgcn_s_barrier();
    __builtin_amdgcn_sched_barrier(0);
  };

  // prologue: tile 0 into buf0
  stage32(Ab, 0, A0, w, lane);
  stage32(Bb, 0, B0, w, lane);
  asm volatile("s_waitcnt vmcnt(0)");
  __builtin_amdgcn_sched_barrier(0);
  __builtin_amdgcn_s_barrier();
  __builtin_amdgcn_sched_barrier(0);

#pragma unroll 1
  for (int t = 0; t < 16; t += 2) {
    step(t,     A0, B0, A1, B1);
    step(t + 1, A1, B1, A0, B0);
  }

  // ---------------- epilogues ----------------
  const int fcol = lane & 15;
  const int frow = (lane >> 4) * 4;
  const int bb0 = (row_off + (int)arow0) >> 10;  // batch idx, uniform per tile

  if (EPI == 0) {
    if (tn < 4) {
      // z quadrant -> fragment-order store
      const size_t foff = ((size_t)(tm * 4 + tn)) * 16384 + (size_t)tid * 64;
      __bf16* zw = (__bf16*)zf;
#pragma unroll
      for (int mi = 0; mi < 4; ++mi) {
        bf16x8 p0, p1;
#pragma unroll
        for (int ni = 0; ni < 4; ++ni)
#pragma unroll
          for (int j = 0; j < 4; ++j) {
            const int gcol = brow0 + wc + ni * 16 + fcol;
            float c = acc[mi][ni][j] + bias[gcol];
            if (L0) c += cterm[bb0 * 1024 + gcol];
            const float v = sigmoidf_(c);
            const int idx = ni * 4 + j;
            if (idx < 8) p0[idx] = (__bf16)v; else p1[idx - 8] = (__bf16)v;
          }
        *(bf16x8*)(zw + foff + mi * 16) = p0;
        *(bf16x8*)(zw + foff + mi * 16 + 8) = p1;
      }
    } else if (tn < 8) {
      // r quadrant -> r*h row-major (h LDS-tiled for L>=1)
      if (!L0) stage_ht(haux + arow0 * 512 + (tn - 4) * 128, smem, w, lane);
#pragma unroll
      for (int mi = 0; mi < 4; ++mi)
#pragma unroll
        for (int ni = 0; ni < 4; ++ni)
#pragma unroll
          for (int j = 0; j < 4; ++j) {
            const int rloc = (int)arow0 + wr + mi * 16 + frow + j;
            const int gcol = brow0 + wc + ni * 16 + fcol;
            const int nn = gcol - 512;
            float c = acc[mi][ni][j] + bias[gcol];
            if (L0) c += cterm[bb0 * 1024 + gcol];
            const float rv = sigmoidf_(c);
            const float h = L0 ? h0f[bb0 * 1536 + nn]
                               : (float)smem[(wr + mi * 16 + frow + j) * 128 + wc + ni * 16 + fcol];
            o_rh[(size_t)rloc * 512 + nn] = (__bf16)(rv * h);
          }
    } else {
      // g-partial quadrant -> fragment-order store (raw, no activation)
      const size_t foff = ((size_t)(tm * 4 + (tn - 8))) * 16384 + (size_t)tid * 64;
      __bf16* gw = (__bf16*)gf;
#pragma unroll
      for (int mi = 0; mi < 4; ++mi) {
        bf16x8 p0, p1;
#pragma unroll
        for (int ni = 0; ni < 4; ++ni)
#pragma unroll
          for (int j = 0; j < 4; ++j) {
            const int gcol = brow0 + wc + ni * 16 + fcol;
            const float v = acc[mi][ni][j] + bias[gcol];
            const int idx = ni * 4 + j;
            if (idx < 8) p0[idx] = (__bf16)v; else p1[idx - 8] = (__bf16)v;
          }
        *(bf16x8*)(gw + foff + mi * 16) = p0;
        *(bf16x8*)(gw + foff + mi * 16 + 8) = p1;
      }
    }
  } else if (EPI == 1) {
    if (!L0) stage_ht(haux + arow0 * 512 + tn * 128, smem, w, lane);
    const size_t foff = ((size_t)(tm * 4 + tn)) * 16384 + (size_t)tid * 64;
    const bool has_last = (o_f != nullptr) && ((tm & 7) == 7);
#pragma unroll
    for (int mi = 0; mi < 4; ++mi) {
      const bf16x8 z0 = *(const bf16x8*)(zf + foff + mi * 16);
      const bf16x8 z1 = *(const bf16x8*)(zf + foff + mi * 16 + 8);
      const bf16x8 g0 = *(const bf16x8*)(gf + foff + mi * 16);
      const bf16x8 g1 = *(const bf16x8*)(gf + foff + mi * 16 + 8);
#pragma unroll
      for (int ni = 0; ni < 4; ++ni)
#pragma unroll
        for (int j = 0; j < 4; ++j) {
          const int rloc = (int)arow0 + wr + mi * 16 + frow + j;
          const int gcol = brow0 + wc + ni * 16 + fcol;
          const int idx = ni * 4 + j;
          const float zv = (float)(idx < 8 ? z0[idx] : z1[idx - 8]);
          const float gp = (float)(idx < 8 ? g0[idx] : g1[idx - 8]);
          const float gv = tanh_fast(gp + acc[mi][ni][j]);
          const float h = L0 ? h0f[bb0 * 1536 + gcol]
                             : (float)smem[(wr + mi * 16 + frow + j) * 128 + wc + ni * 16 + fcol];
          const float hv = zv * h + (1.f - zv) * gv;
          o_h[(size_t)rloc * 512 + gcol] = (__bf16)hv;
          if (has_last && ((rloc & 1023) == 1023))
            o_f[(size_t)bb0 * 1536 + gcol] = (float)(__bf16)hv;
        }
    }
  } else {
#pragma unroll
    for (int mi = 0; mi < 4; ++mi)
#pragma unroll
      for (int ni = 0; ni < 4; ++ni)
#pragma unroll
        for (int j = 0; j < 4; ++j) {
          const int rloc = (int)arow0 + wr + mi * 16 + frow + j;
          const int gcol = brow0 + wc + ni * 16 + fcol;
          o_f[(size_t)rloc * 512 + gcol] = acc[mi][ni][j] + bias[gcol];
        }
  }
}

// ---- prep kernels (unchanged, passing) ----

__global__ void prep_pack(const float* __restrict__ Wzx, const float* __restrict__ Wzh,
                          const float* __restrict__ Wrx, const float* __restrict__ Wrh,
                          const float* __restrict__ Wgx, const float* __restrict__ Wgh,
                          const float* __restrict__ Wout,
                          __bf16* __restrict__ W1t, __bf16* __restrict__ Wght,
                          __bf16* __restrict__ Woutt)
{
  const int slot = blockIdx.z;
  const float* srcA;
  const float* srcB = nullptr;
  __bf16* dst;
  if (slot < 9) {
    const int l = slot / 3, g = slot % 3;
    srcA = (g == 0 ? Wzx : g == 1 ? Wrx : Wgx) + (size_t)l * 512 * 512;
    if (l > 0 && g < 2) srcB = (g == 0 ? Wzh : Wrh) + (size_t)l * 512 * 512;
    dst = W1t + (size_t)l * 1536 * 512 + (size_t)g * 512 * 512;
  } else if (slot < 12) {
    const int l = slot - 9;
    srcA = Wgh + (size_t)l * 512 * 512;
    dst = Wght + (size_t)l * 512 * 512;
  } else {
    srcA = Wout;
    dst = Woutt;
  }
  __shared__ float tile[32][33];
  const int k0 = blockIdx.x * 32;
  const int n0 = blockIdx.y * 32;
  const int tx = threadIdx.x;
  const int ty = threadIdx.y;
  for (int i = ty; i < 32; i += 8) {
    float v = srcA[(size_t)(k0 + i) * 512 + n0 + tx];
    if (srcB) v += srcB[(size_t)(k0 + i) * 512 + n0 + tx];
    tile[i][tx] = v;
  }
  __syncthreads();
  for (int i = ty; i < 32; i += 8)
    dst[(size_t)(n0 + i) * 512 + k0 + tx] = (__bf16)tile[tx][i];
}

__global__ void cterm_kernel(const float* __restrict__ hidden,
                             const float* __restrict__ Wzh,
                             const float* __restrict__ Wrh,
                             float* __restrict__ Cterm)
{
  const int idx = blockIdx.x * blockDim.x + threadIdx.x;
  const int b = idx >> 10;
  const int n = idx & 1023;
  const float* W = (n < 512 ? Wzh : Wrh);
  const int nn = n & 511;
  const float* h0 = hidden + (size_t)b * 1536;
  float acc = 0.f;
  for (int k = 0; k < 512; ++k) acc += h0[k] * W[(size_t)k * 512 + nn];
  Cterm[idx] = acc;
}

__global__ void small_prep(const float* __restrict__ bzx, const float* __restrict__ brx,
                           const float* __restrict__ bgx, const float* __restrict__ hidden,
                           float* __restrict__ bias1, float* __restrict__ out_hidden)
{
  const int idx = blockIdx.x * blockDim.x + threadIdx.x;
  if (idx < 3 * 1536) {
    const int l = idx / 1536, j = idx % 1536;
    const float* src = (j < 512 ? bzx : j < 1024 ? brx : bgx);
    bias1[idx] = src[l * 512 + (j & 511)];
  }
  const int hidx = idx - 3 * 1536;
  if (hidx >= 0 && hidx < 64 * 512) {
    const int b = hidx >> 9, n = hidx & 511;
    out_hidden[(size_t)b * 1536 + n] = hidden[(size_t)b * 1536 + n];
  }
}

__global__ void convert_x(const float* __restrict__ src, __bf16* __restrict__ dst, long n)
{
  const long i = ((long)blockIdx.x * blockDim.x + threadIdx.x) * 8;
  if (i >= n) return;
  const f32x4 a = *(const f32x4*)(src + i);
  const f32x4 b = *(const f32x4*)(src + i + 4);
  bf16x8 o;
  o[0] = (__bf16)a[0]; o[1] = (__bf16)a[1]; o[2] = (__bf16)a[2]; o[3] = (__bf16)a[3];
  o[4] = (__bf16)b[0]; o[5] = (__bf16)b[1]; o[6] = (__bf16)b[2]; o[7] = (__bf16)b[3];
  *(bf16x8*)(dst + i) = o;
}

extern "C" void kernel_launch(void* const* d_in, const int* in_sizes, int n_in,
                              void* d_out, int out_size, void* d_ws, size_t ws_size,
                              hipStream_t stream) {
  const float* input  = (const float*)d_in[0];
  const float* hidden = (const float*)d_in[1];
  const float* Wzx = (const float*)d_in[2];
  const float* bzx = (const float*)d_in[3];
  const float* Wzh = (const float*)d_in[4];
  const float* Wrx = (const float*)d_in[5];
  const float* brx = (const float*)d_in[6];
  const float* Wrh = (const float*)d_in[7];
  const float* Wgx = (const float*)d_in[8];
  const float* bgx = (const float*)d_in[9];
  const float* Wgh = (const float*)d_in[10];
  const float* Wout = (const float*)d_in[11];
  const float* bout = (const float*)d_in[12];

  float* out = (float*)d_out;
  float* out_hidden = out + HID_OFF;

  char* ws = (char*)d_ws;
  size_t off = 0;
  auto carve = [&](size_t bytes) -> void* {
    off = (off + 255) & ~(size_t)255;
    void* p = ws + off;
    off += bytes;
    return p;
  };

  __bf16* W1t   = (__bf16*)carve(3ull * 1536 * 512 * 2);
  __bf16* Wght  = (__bf16*)carve(3ull * 512 * 512 * 2);
  __bf16* Woutt = (__bf16*)carve(512ull * 512 * 2);
  float*  bias1 = (float*) carve(3ull * 1536 * 4);
  float*  Cterm = (float*) carve(64ull * 1024 * 4);
  const size_t fixed_end = off;

  long chunk_rows = NROWS;
  int C = 1;
  while (C < 32) {
    const size_t need = ((fixed_end + 255) & ~(size_t)255) +
                        5ull * (size_t)chunk_rows * 512 * 2 + 5 * 256;
    if (need <= ws_size) break;
    C *= 2;
    chunk_rows /= 2;
  }
  __bf16* bufA  = (__bf16*)carve((size_t)chunk_rows * 512 * 2);
  __bf16* bufB  = (__bf16*)carve((size_t)chunk_rows * 512 * 2);
  __bf16* zfrag = (__bf16*)carve((size_t)chunk_rows * 512 * 2);
  __bf16* rhb   = (__bf16*)carve((size_t)chunk_rows * 512 * 2);
  __bf16* gfrag = (__bf16*)carve((size_t)chunk_rows * 512 * 2);

  small_prep<<<(3 * 1536 + 64 * 512 + 255) / 256, 256, 0, stream>>>(
      bzx, brx, bgx, hidden, bias1, out_hidden);
  dim3 tp_grid(16, 16, 13), tp_blk(32, 8);
  prep_pack<<<tp_grid, tp_blk, 0, stream>>>(Wzx, Wzh, Wrx, Wrh, Wgx, Wgh, Wout,
                                            W1t, Wght, Woutt);
  cterm_kernel<<<65536 / 256, 256, 0, stream>>>(hidden, Wzh, Wrh, Cterm);

  for (int c = 0; c < C; ++c) {
    const long row_off = (long)c * chunk_rows;
    const long nelem = chunk_rows * 512;
    const int mt = (int)(chunk_rows / 128);

    convert_x<<<(int)((nelem / 8 + 255) / 256), 256, 0, stream>>>(
        input + (size_t)row_off * 512, bufA, nelem);

    // layer 0
    gemm7<0, true><<<mt * 12, 256, 0, stream>>>(
        bufA, W1t, 12, (int)row_off, bias1, Cterm, hidden, nullptr,
        zfrag, gfrag, rhb, nullptr, nullptr);
    gemm7<1, true><<<mt * 4, 256, 0, stream>>>(
        rhb, Wght, 4, (int)row_off, nullptr, nullptr, hidden, nullptr,
        zfrag, gfrag, nullptr, bufB, out_hidden + 512);

    // layer 1 (x == h == bufB)
    gemm7<0, false><<<mt * 12, 256, 0, stream>>>(
        bufB, W1t + 1536 * 512, 12, (int)row_off, bias1 + 1536, nullptr, nullptr, bufB,
        zfrag, gfrag, rhb, nullptr, nullptr);
    gemm7<1, false><<<mt * 4, 256, 0, stream>>>(
        rhb, Wght + 512 * 512, 4, (int)row_off, nullptr, nullptr, nullptr, bufB,
        zfrag, gfrag, nullptr, bufA, out_hidden + 1024);

    // layer 2 (x == h == bufA)
    gemm7<0, false><<<mt * 12, 256, 0, stream>>>(
        bufA, W1t + 2 * 1536 * 512, 12, (int)row_off, bias1 + 3072, nullptr, nullptr, bufA,
        zfrag, gfrag, rhb, nullptr, nullptr);
    gemm7<1, false><<<mt * 4, 256, 0, stream>>>(
        rhb, Wght + 2 * 512 * 512, 4, (int)row_off, nullptr, nullptr, nullptr, bufA,
        zfrag, gfrag, nullptr, bufB, nullptr);

    // output projection
    gemm7<2, false><<<mt * 4, 256, 0, stream>>>(
        bufB, Woutt, 4, (int)row_off, bout, nullptr, nullptr, nullptr,
        nullptr, nullptr, nullptr, nullptr, out + (size_t)row_off * 512);
  }
}

// Round 9
// 863.081 us; speedup vs baseline: 1.8155x; 1.0747x over previous
//
#include <hip/hip_runtime.h>

// MultilayerGRU — reference's indexing bug makes every (b,t) independent:
// 7 chained GEMMs over a 65536x512 activation matrix.
// Round 9 = Round 8 with the vmcnt arithmetic FIXED: one staged A+B tile pair
// = 4 loads/wave (2 gload_lds per stage32), so depth-2 pipelining needs
// vmcnt(4) (tile t+1 landed, t+2 in flight), NOT vmcnt(8) (no-op -> race,
// R8's absmax 5.06). Swizzle (2-way-free: slot = (lane>>4) ^ ((row>>1)&3))
// and triple-buffer rotation kept from R8 — both re-audited correct.

typedef __attribute__((ext_vector_type(4))) float f32x4;
typedef __attribute__((ext_vector_type(8))) __bf16 bf16x8;

#define NROWS 65536          // B*S
#define HID_OFF 33554432ull  // B*S*O floats, start of hidden_out in d_out

__device__ __forceinline__ void gload16(const void* g, void* l) {
  __builtin_amdgcn_global_load_lds((const __attribute__((address_space(1))) void*)g,
                                   (__attribute__((address_space(3))) void*)l,
                                   16, 0, 0);
}
__device__ __forceinline__ float sigmoidf_(float x) { return 1.f / (1.f + __expf(-x)); }
__device__ __forceinline__ float tanh_fast(float x) {
  const float e = __expf(2.f * x);
  return 1.f - 2.f / (e + 1.f);
}

// Stage one 128x32 bf16 tile (8KB) with 256 threads into linear LDS.
// LDS[row][slot] holds global chunk (slot ^ ((row>>1)&3)) so the swizzled
// read below is bank-conflict-free (each quarter-wave hits all 8 bank-quads
// exactly twice; 2-way is free per m136).
__device__ __forceinline__ void stage32(const __bf16* __restrict__ src, int k0,
                                        __bf16* lds, int w, int lane) {
#pragma unroll
  for (int i = 0; i < 2; ++i) {
    const int s0 = (w * 2 + i) * 64;   // wave-uniform chunk base
    const int s = s0 + lane;           // chunk 0..511
    const int row = s >> 2;            // 0..127
    const int cc = ((s & 3) ^ (row >> 1)) & 3;   // source chunk within row
    gload16(src + (size_t)row * 512 + k0 + cc * 8, lds + s0 * 8);
  }
}

// Swizzled fragment read from a [128][32] tile: slot = (lane>>4) ^ ((row>>1)&3).
__device__ __forceinline__ bf16x8 frag32(const __bf16* t, int row, int lane) {
  const int c = (((lane >> 4) ^ (row >> 1)) & 3);
  return *(const bf16x8*)(t + row * 32 + c * 8);
}

// Stage a 128x128 bf16 tile of haux (512-col row-major) into 32KB LDS.
__device__ __forceinline__ void stage_ht(const __bf16* __restrict__ src,
                                         __bf16* Ht, int w, int lane) {
#pragma unroll
  for (int i = 0; i < 8; ++i) {
    const int s0 = i * 256 + w * 64;   // 16B chunks, 16 per row
    const int s = s0 + lane;
    const int row = s >> 4, cc = s & 15;
    gload16(src + (size_t)row * 512 + cc * 8, Ht + s0 * 8);
  }
  asm volatile("s_waitcnt vmcnt(0)");
  __builtin_amdgcn_sched_barrier(0);
  __builtin_amdgcn_s_barrier();
  __builtin_amdgcn_sched_barrier(0);
}

// EPI: 0 = gates (N=1536: z|r|gpart), 1 = update (N=512), 2 = out (N=512)
template<int EPI, bool L0>
__global__ __launch_bounds__(256, 3) void gemm9(
    const __bf16* __restrict__ A,     // M x 512 row-major
    const __bf16* __restrict__ Bt,    // N x 512 (pre-transposed weights)
    int tiles_n, int row_off,
    const float* __restrict__ bias,
    const float* __restrict__ cterm,  // L0 gates: 64 x 1024 fp32
    const float* __restrict__ h0f,    // L0: hidden_state base (B x 3*512)
    const __bf16* __restrict__ haux,  // L>=1: h row-major
    const __bf16* __restrict__ zf,    // fragment buffer (EPI0 write / EPI1 read)
    const __bf16* __restrict__ gf,    // fragment buffer (EPI0 write / EPI1 read)
    __bf16* __restrict__ o_rh,        // EPI0: r*h row-major
    __bf16* __restrict__ o_h,         // EPI1: h row-major
    float* __restrict__ o_f)          // EPI1: hidden_out slot; EPI2: out
{
  __shared__ alignas(16) __bf16 smem[24576];   // 48KB: 3 x (A 8KB + B 8KB)
  __bf16* const A0 = smem;
  __bf16* const B0 = smem + 4096;
  __bf16* const A1 = smem + 8192;
  __bf16* const B1 = smem + 12288;
  __bf16* const A2 = smem + 16384;
  __bf16* const B2 = smem + 20480;

  const int tid = threadIdx.x, lane = tid & 63, w = tid >> 6;

  // T1: bijective XCD swizzle (m204)
  int bid = blockIdx.x;
  {
    const int nwg = gridDim.x;
    const int q = nwg >> 3, r = nwg & 7;
    const int x = bid & 7, rest = bid >> 3;
    bid = (x < r ? x * (q + 1) : r * (q + 1) + (x - r) * q) + rest;
  }
  const int tm = bid / tiles_n;
  const int tn = bid - tm * tiles_n;
  const size_t arow0 = (size_t)tm * 128;
  const int brow0 = tn * 128;
  const __bf16* const Ab = A + arow0 * 512;
  const __bf16* const Bb = Bt + (size_t)brow0 * 512;

  const int wr = (w >> 1) * 64;
  const int wc = (w & 1) * 64;

  f32x4 acc[4][4];
  const f32x4 zz = {0.f, 0.f, 0.f, 0.f};
#pragma unroll
  for (int i = 0; i < 4; ++i)
#pragma unroll
    for (int j = 0; j < 4; ++j) acc[i][j] = zz;

  // one k-step: stage tile t+2 (depth-2), compute tile t.
  // waits: vm=4 -> tile t+1 landed (t+2's 4 loads stay in flight);
  //        vm=0 -> drain; vm=-1 -> none (last step).
  auto stepf = [&](int t, const __bf16* cA, const __bf16* cB,
                   __bf16* nA, __bf16* nB, int vm) {
    if (nA) {
      stage32(Ab, (t + 2) * 32, nA, w, lane);
      stage32(Bb, (t + 2) * 32, nB, w, lane);
    }
    bf16x8 af[4], bb4[4];
#pragma unroll
    for (int i = 0; i < 4; ++i) {
      af[i]  = frag32(cA, wr + i * 16 + (lane & 15), lane);
      bb4[i] = frag32(cB, wc + i * 16 + (lane & 15), lane);
    }
#pragma unroll
    for (int mi = 0; mi < 4; ++mi)
#pragma unroll
      for (int ni = 0; ni < 4; ++ni)
        acc[mi][ni] = __builtin_amdgcn_mfma_f32_16x16x32_bf16(af[mi], bb4[ni], acc[mi][ni], 0, 0, 0);
    if (vm == 4) {
      asm volatile("s_waitcnt vmcnt(4)");
      __builtin_amdgcn_sched_barrier(0);
    } else if (vm == 0) {
      asm volatile("s_waitcnt vmcnt(0)");
      __builtin_amdgcn_sched_barrier(0);
    }
    __builtin_amdgcn_s_barrier();
    __builtin_amdgcn_sched_barrier(0);
  };

  // prologue: stage tiles 0 and 1 (8 loads/wave); vmcnt(4) -> tile 0 landed,
  // tile 1 (4 loads) still in flight.
  stage32(Ab, 0, A0, w, lane);
  stage32(Bb, 0, B0, w, lane);
  stage32(Ab, 32, A1, w, lane);
  stage32(Bb, 32, B1, w, lane);
  asm volatile("s_waitcnt vmcnt(4)");
  __builtin_amdgcn_sched_barrier(0);
  __builtin_amdgcn_s_barrier();
  __builtin_amdgcn_sched_barrier(0);

  // steps 0..11 (stage t+2 <= 13)
#pragma unroll 1
  for (int it = 0; it < 4; ++it) {
    const int t = it * 3;
    stepf(t,     A0, B0, A2, B2, 4);
    stepf(t + 1, A1, B1, A0, B0, 4);
    stepf(t + 2, A2, B2, A1, B1, 4);
  }
  // tail: t=12 stages 14, t=13 stages 15, t=14 drains, t=15 computes last
  stepf(12, A0, B0, A2, B2, 4);
  stepf(13, A1, B1, A0, B0, 4);
  stepf(14, A2, B2, nullptr, nullptr, 0);
  stepf(15, A0, B0, nullptr, nullptr, -1);

  // ---------------- epilogues ----------------
  const int fcol = lane & 15;
  const int frow = (lane >> 4) * 4;
  const int bb0 = (row_off + (int)arow0) >> 10;  // batch idx, uniform per tile

  if (EPI == 0) {
    if (tn < 4) {
      // z quadrant -> fragment-order store
      const size_t foff = ((size_t)(tm * 4 + tn)) * 16384 + (size_t)tid * 64;
      __bf16* zw = (__bf16*)zf;
#pragma unroll
      for (int mi = 0; mi < 4; ++mi) {
        bf16x8 p0, p1;
#pragma unroll
        for (int ni = 0; ni < 4; ++ni)
#pragma unroll
          for (int j = 0; j < 4; ++j) {
            const int gcol = brow0 + wc + ni * 16 + fcol;
            float c = acc[mi][ni][j] + bias[gcol];
            if (L0) c += cterm[bb0 * 1024 + gcol];
            const float v = sigmoidf_(c);
            const int idx = ni * 4 + j;
            if (idx < 8) p0[idx] = (__bf16)v; else p1[idx - 8] = (__bf16)v;
          }
        *(bf16x8*)(zw + foff + mi * 16) = p0;
        *(bf16x8*)(zw + foff + mi * 16 + 8) = p1;
      }
    } else if (tn < 8) {
      // r quadrant -> r*h row-major (h LDS-tiled for L>=1)
      if (!L0) stage_ht(haux + arow0 * 512 + (tn - 4) * 128, smem, w, lane);
#pragma unroll
      for (int mi = 0; mi < 4; ++mi)
#pragma unroll
        for (int ni = 0; ni < 4; ++ni)
#pragma unroll
          for (int j = 0; j < 4; ++j) {
            const int rloc = (int)arow0 + wr + mi * 16 + frow + j;
            const int gcol = brow0 + wc + ni * 16 + fcol;
            const int nn = gcol - 512;
            float c = acc[mi][ni][j] + bias[gcol];
            if (L0) c += cterm[bb0 * 1024 + gcol];
            const float rv = sigmoidf_(c);
            const float h = L0 ? h0f[bb0 * 1536 + nn]
                               : (float)smem[(wr + mi * 16 + frow + j) * 128 + wc + ni * 16 + fcol];
            o_rh[(size_t)rloc * 512 + nn] = (__bf16)(rv * h);
          }
    } else {
      // g-partial quadrant -> fragment-order store (raw, no activation)
      const size_t foff = ((size_t)(tm * 4 + (tn - 8))) * 16384 + (size_t)tid * 64;
      __bf16* gw = (__bf16*)gf;
#pragma unroll
      for (int mi = 0; mi < 4; ++mi) {
        bf16x8 p0, p1;
#pragma unroll
        for (int ni = 0; ni < 4; ++ni)
#pragma unroll
          for (int j = 0; j < 4; ++j) {
            const int gcol = brow0 + wc + ni * 16 + fcol;
            const float v = acc[mi][ni][j] + bias[gcol];
            const int idx = ni * 4 + j;
            if (idx < 8) p0[idx] = (__bf16)v; else p1[idx - 8] = (__bf16)v;
          }
        *(bf16x8*)(gw + foff + mi * 16) = p0;
        *(bf16x8*)(gw + foff + mi * 16 + 8) = p1;
      }
    }
  } else if (EPI == 1) {
    // prefetch z/g fragments first (overlaps with stage_ht latency)
    const size_t foff = ((size_t)(tm * 4 + tn)) * 16384 + (size_t)tid * 64;
    bf16x8 zr[4][2], gr[4][2];
#pragma unroll
    for (int mi = 0; mi < 4; ++mi) {
      zr[mi][0] = *(const bf16x8*)(zf + foff + mi * 16);
      zr[mi][1] = *(const bf16x8*)(zf + foff + mi * 16 + 8);
      gr[mi][0] = *(const bf16x8*)(gf + foff + mi * 16);
      gr[mi][1] = *(const bf16x8*)(gf + foff + mi * 16 + 8);
    }
    if (!L0) stage_ht(haux + arow0 * 512 + tn * 128, smem, w, lane);
    const bool has_last = (o_f != nullptr) && ((tm & 7) == 7);
#pragma unroll
    for (int mi = 0; mi < 4; ++mi) {
#pragma unroll
      for (int ni = 0; ni < 4; ++ni)
#pragma unroll
        for (int j = 0; j < 4; ++j) {
          const int rloc = (int)arow0 + wr + mi * 16 + frow + j;
          const int gcol = brow0 + wc + ni * 16 + fcol;
          const int idx = ni * 4 + j;
          const float zv = (float)(idx < 8 ? zr[mi][0][idx] : zr[mi][1][idx - 8]);
          const float gp = (float)(idx < 8 ? gr[mi][0][idx] : gr[mi][1][idx - 8]);
          const float gv = tanh_fast(gp + acc[mi][ni][j]);
          const float h = L0 ? h0f[bb0 * 1536 + gcol]
                             : (float)smem[(wr + mi * 16 + frow + j) * 128 + wc + ni * 16 + fcol];
          const float hv = zv * h + (1.f - zv) * gv;
          o_h[(size_t)rloc * 512 + gcol] = (__bf16)hv;
          if (has_last && ((rloc & 1023) == 1023))
            o_f[(size_t)bb0 * 1536 + gcol] = (float)(__bf16)hv;
        }
    }
  } else {
#pragma unroll
    for (int mi = 0; mi < 4; ++mi)
#pragma unroll
      for (int ni = 0; ni < 4; ++ni)
#pragma unroll
        for (int j = 0; j < 4; ++j) {
          const int rloc = (int)arow0 + wr + mi * 16 + frow + j;
          const int gcol = brow0 + wc + ni * 16 + fcol;
          o_f[(size_t)rloc * 512 + gcol] = acc[mi][ni][j] + bias[gcol];
        }
  }
}

// ---- prep kernels (unchanged, passing) ----

__global__ void prep_pack(const float* __restrict__ Wzx, const float* __restrict__ Wzh,
                          const float* __restrict__ Wrx, const float* __restrict__ Wrh,
                          const float* __restrict__ Wgx, const float* __restrict__ Wgh,
                          const float* __restrict__ Wout,
                          __bf16* __restrict__ W1t, __bf16* __restrict__ Wght,
                          __bf16* __restrict__ Woutt)
{
  const int slot = blockIdx.z;
  const float* srcA;
  const float* srcB = nullptr;
  __bf16* dst;
  if (slot < 9) {
    const int l = slot / 3, g = slot % 3;
    srcA = (g == 0 ? Wzx : g == 1 ? Wrx : Wgx) + (size_t)l * 512 * 512;
    if (l > 0 && g < 2) srcB = (g == 0 ? Wzh : Wrh) + (size_t)l * 512 * 512;
    dst = W1t + (size_t)l * 1536 * 512 + (size_t)g * 512 * 512;
  } else if (slot < 12) {
    const int l = slot - 9;
    srcA = Wgh + (size_t)l * 512 * 512;
    dst = Wght + (size_t)l * 512 * 512;
  } else {
    srcA = Wout;
    dst = Woutt;
  }
  __shared__ float tile[32][33];
  const int k0 = blockIdx.x * 32;
  const int n0 = blockIdx.y * 32;
  const int tx = threadIdx.x;
  const int ty = threadIdx.y;
  for (int i = ty; i < 32; i += 8) {
    float v = srcA[(size_t)(k0 + i) * 512 + n0 + tx];
    if (srcB) v += srcB[(size_t)(k0 + i) * 512 + n0 + tx];
    tile[i][tx] = v;
  }
  __syncthreads();
  for (int i = ty; i < 32; i += 8)
    dst[(size_t)(n0 + i) * 512 + k0 + tx] = (__bf16)tile[tx][i];
}

__global__ void cterm_kernel(const float* __restrict__ hidden,
                             const float* __restrict__ Wzh,
                             const float* __restrict__ Wrh,
                             float* __restrict__ Cterm)
{
  const int idx = blockIdx.x * blockDim.x + threadIdx.x;
  const int b = idx >> 10;
  const int n = idx & 1023;
  const float* W = (n < 512 ? Wzh : Wrh);
  const int nn = n & 511;
  const float* h0 = hidden + (size_t)b * 1536;
  float acc = 0.f;
  for (int k = 0; k < 512; ++k) acc += h0[k] * W[(size_t)k * 512 + nn];
  Cterm[idx] = acc;
}

__global__ void small_prep(const float* __restrict__ bzx, const float* __restrict__ brx,
                           const float* __restrict__ bgx, const float* __restrict__ hidden,
                           float* __restrict__ bias1, float* __restrict__ out_hidden)
{
  const int idx = blockIdx.x * blockDim.x + threadIdx.x;
  if (idx < 3 * 1536) {
    const int l = idx / 1536, j = idx % 1536;
    const float* src = (j < 512 ? bzx : j < 1024 ? brx : bgx);
    bias1[idx] = src[l * 512 + (j & 511)];
  }
  const int hidx = idx - 3 * 1536;
  if (hidx >= 0 && hidx < 64 * 512) {
    const int b = hidx >> 9, n = hidx & 511;
    out_hidden[(size_t)b * 1536 + n] = hidden[(size_t)b * 1536 + n];
  }
}

__global__ void convert_x(const float* __restrict__ src, __bf16* __restrict__ dst, long n)
{
  const long i = ((long)blockIdx.x * blockDim.x + threadIdx.x) * 8;
  if (i >= n) return;
  const f32x4 a = *(const f32x4*)(src + i);
  const f32x4 b = *(const f32x4*)(src + i + 4);
  bf16x8 o;
  o[0] = (__bf16)a[0]; o[1] = (__bf16)a[1]; o[2] = (__bf16)a[2]; o[3] = (__bf16)a[3];
  o[4] = (__bf16)b[0]; o[5] = (__bf16)b[1]; o[6] = (__bf16)b[2]; o[7] = (__bf16)b[3];
  *(bf16x8*)(dst + i) = o;
}

extern "C" void kernel_launch(void* const* d_in, const int* in_sizes, int n_in,
                              void* d_out, int out_size, void* d_ws, size_t ws_size,
                              hipStream_t stream) {
  const float* input  = (const float*)d_in[0];
  const float* hidden = (const float*)d_in[1];
  const float* Wzx = (const float*)d_in[2];
  const float* bzx = (const float*)d_in[3];
  const float* Wzh = (const float*)d_in[4];
  const float* Wrx = (const float*)d_in[5];
  const float* brx = (const float*)d_in[6];
  const float* Wrh = (const float*)d_in[7];
  const float* Wgx = (const float*)d_in[8];
  const float* bgx = (const float*)d_in[9];
  const float* Wgh = (const float*)d_in[10];
  const float* Wout = (const float*)d_in[11];
  const float* bout = (const float*)d_in[12];

  float* out = (float*)d_out;
  float* out_hidden = out + HID_OFF;

  char* ws = (char*)d_ws;
  size_t off = 0;
  auto carve = [&](size_t bytes) -> void* {
    off = (off + 255) & ~(size_t)255;
    void* p = ws + off;
    off += bytes;
    return p;
  };

  __bf16* W1t   = (__bf16*)carve(3ull * 1536 * 512 * 2);
  __bf16* Wght  = (__bf16*)carve(3ull * 512 * 512 * 2);
  __bf16* Woutt = (__bf16*)carve(512ull * 512 * 2);
  float*  bias1 = (float*) carve(3ull * 1536 * 4);
  float*  Cterm = (float*) carve(64ull * 1024 * 4);
  const size_t fixed_end = off;

  long chunk_rows = NROWS;
  int C = 1;
  while (C < 32) {
    const size_t need = ((fixed_end + 255) & ~(size_t)255) +
                        5ull * (size_t)chunk_rows * 512 * 2 + 5 * 256;
    if (need <= ws_size) break;
    C *= 2;
    chunk_rows /= 2;
  }
  __bf16* bufA  = (__bf16*)carve((size_t)chunk_rows * 512 * 2);
  __bf16* bufB  = (__bf16*)carve((size_t)chunk_rows * 512 * 2);
  __bf16* zfrag = (__bf16*)carve((size_t)chunk_rows * 512 * 2);
  __bf16* rhb   = (__bf16*)carve((size_t)chunk_rows * 512 * 2);
  __bf16* gfrag = (__bf16*)carve((size_t)chunk_rows * 512 * 2);

  small_prep<<<(3 * 1536 + 64 * 512 + 255) / 256, 256, 0, stream>>>(
      bzx, brx, bgx, hidden, bias1, out_hidden);
  dim3 tp_grid(16, 16, 13), tp_blk(32, 8);
  prep_pack<<<tp_grid, tp_blk, 0, stream>>>(Wzx, Wzh, Wrx, Wrh, Wgx, Wgh, Wout,
                                            W1t, Wght, Woutt);
  cterm_kernel<<<65536 / 256, 256, 0, stream>>>(hidden, Wzh, Wrh, Cterm);

  for (int c = 0; c < C; ++c) {
    const long row_off = (long)c * chunk_rows;
    const long nelem = chunk_rows * 512;
    const int mt = (int)(chunk_rows / 128);

    convert_x<<<(int)((nelem / 8 + 255) / 256), 256, 0, stream>>>(
        input + (size_t)row_off * 512, bufA, nelem);

    // layer 0
    gemm9<0, true><<<mt * 12, 256, 0, stream>>>(
        bufA, W1t, 12, (int)row_off, bias1, Cterm, hidden, nullptr,
        zfrag, gfrag, rhb, nullptr, nullptr);
    gemm9<1, true><<<mt * 4, 256, 0, stream>>>(
        rhb, Wght, 4, (int)row_off, nullptr, nullptr, hidden, nullptr,
        zfrag, gfrag, nullptr, bufB, out_hidden + 512);

    // layer 1 (x == h == bufB)
    gemm9<0, false><<<mt * 12, 256, 0, stream>>>(
        bufB, W1t + 1536 * 512, 12, (int)row_off, bias1 + 1536, nullptr, nullptr, bufB,
        zfrag, gfrag, rhb, nullptr, nullptr);
    gemm9<1, false><<<mt * 4, 256, 0, stream>>>(
        rhb, Wght + 512 * 512, 4, (int)row_off, nullptr, nullptr, nullptr, bufB,
        zfrag, gfrag, nullptr, bufA, out_hidden + 1024);

    // layer 2 (x == h == bufA)
    gemm9<0, false><<<mt * 12, 256, 0, stream>>>(
        bufA, W1t + 2 * 1536 * 512, 12, (int)row_off, bias1 + 3072, nullptr, nullptr, bufA,
        zfrag, gfrag, rhb, nullptr, nullptr);
    gemm9<1, false><<<mt * 4, 256, 0, stream>>>(
        rhb, Wght + 2 * 512 * 512, 4, (int)row_off, nullptr, nullptr, nullptr, bufA,
        zfrag, gfrag, nullptr, bufB, nullptr);

    // output projection
    gemm9<2, false><<<mt * 4, 256, 0, stream>>>(
        bufB, Woutt, 4, (int)row_off, bout, nullptr, nullptr, nullptr,
        nullptr, nullptr, nullptr, nullptr, out + (size_t)row_off * 512);
  }
}